// Round 1
// baseline (479.017 us; speedup 1.0000x reference)
//
#include <hip/hip_runtime.h>
#include <hip/hip_bf16.h>
#include <stdint.h>

#define E_DIM 1024
#define H_NUM 16
#define D_DIM 64
#define B_NUM 4
#define S_LEN 2048
#define M_DIM (B_NUM * S_LEN)  // 8192

typedef short bf16x8 __attribute__((ext_vector_type(8)));
typedef float f32x4 __attribute__((ext_vector_type(4)));
typedef float f32x4v __attribute__((ext_vector_type(4)));
typedef unsigned short u16;
typedef u16 u16x4 __attribute__((ext_vector_type(4)));
typedef u16 u16x8 __attribute__((ext_vector_type(8)));
typedef float fl4 __attribute__((ext_vector_type(4)));

typedef const __attribute__((address_space(1))) void* gas_ptr;
typedef __attribute__((address_space(3))) void* las_ptr;

__device__ __forceinline__ u16 f2bf(float f) {
    uint32_t u = __builtin_bit_cast(uint32_t, f);
    u += 0x7fffu + ((u >> 16) & 1u);   // RNE (inputs finite)
    return (u16)(u >> 16);
}

__device__ __forceinline__ void gload16(const u16* g, u16* l) {
    __builtin_amdgcn_global_load_lds((gas_ptr)g, (las_ptr)l, 16, 0, 0);
}

// ---------------- fp32 -> bf16 conversion (vectorized x4) ----------------
__global__ __launch_bounds__(256) void cvt_kernel(const float* __restrict__ in,
                                                  u16* __restrict__ out, int n4) {
    int idx = blockIdx.x * 256 + threadIdx.x;
    int stride = gridDim.x * 256;
    for (int i = idx; i < n4; i += stride) {
        fl4 v = ((const fl4*)in)[i];
        u16x4 o;
#pragma unroll
        for (int j = 0; j < 4; j++) o[j] = f2bf(v[j]);
        ((u16x4*)out)[i] = o;
    }
}

// ---------------- NT GEMM: C[m,n] = sum_k A[m,k]*B[n,k] + bias[n] --------
// A: [M,K] bf16 row-major. Bw: [N,K] bf16 row-major (weight as stored (f,e)).
// MODE 0: bf16 out at [B,H,S,D]   (Q, K)
// MODE 1: bf16 out at [B,H,D,S]   (V transposed)
// MODE 2: fp32 out at [M,E]       (final output)
template <int MODE>
__global__ __launch_bounds__(256) void gemm_nt(const u16* __restrict__ A,
                                               const u16* __restrict__ Bw,
                                               const float* __restrict__ bias,
                                               void* __restrict__ out) {
    __shared__ u16 Ash[128 * 32];
    __shared__ u16 Bsh[128 * 32];
    const int t = threadIdx.x, w = t >> 6, lane = t & 63;
    const int li = lane & 15, lg = lane >> 4;
    const int m0 = blockIdx.y * 128, n0 = blockIdx.x * 128;
    const int K = 1024;
    const int srow = lane >> 2, scol = (lane & 3) * 8;
    const int wr = (w >> 1) * 64, wc = (w & 1) * 64;
    f32x4 acc[4][4] = {};

    for (int k0 = 0; k0 < K; k0 += 32) {
#pragma unroll
        for (int r = 0; r < 2; r++) {
            int rowbase = r * 64 + w * 16;
            gload16(A + (size_t)(m0 + rowbase + srow) * K + k0 + scol, &Ash[rowbase * 32]);
            gload16(Bw + (size_t)(n0 + rowbase + srow) * K + k0 + scol, &Bsh[rowbase * 32]);
        }
        __syncthreads();
        bf16x8 af[4], bfr[4];
#pragma unroll
        for (int i = 0; i < 4; i++)
            af[i] = *(const bf16x8*)&Ash[(wr + i * 16 + li) * 32 + lg * 8];
#pragma unroll
        for (int j = 0; j < 4; j++)
            bfr[j] = *(const bf16x8*)&Bsh[(wc + j * 16 + li) * 32 + lg * 8];
#pragma unroll
        for (int i = 0; i < 4; i++)
#pragma unroll
            for (int j = 0; j < 4; j++)
                acc[i][j] = __builtin_amdgcn_mfma_f32_16x16x32_bf16(af[i], bfr[j], acc[i][j], 0, 0, 0);
        __syncthreads();
    }

    // epilogue: row = m0+wr+i*16+lg*4+ri, col = n0+wc+j*16+li
#pragma unroll
    for (int i = 0; i < 4; i++) {
#pragma unroll
        for (int j = 0; j < 4; j++) {
            const int col = n0 + wc + j * 16 + li;
            const float bv = bias[col];
            if (MODE == 2) {
                float* o = (float*)out;
#pragma unroll
                for (int ri = 0; ri < 4; ri++) {
                    int row = m0 + wr + i * 16 + lg * 4 + ri;
                    o[(size_t)row * E_DIM + col] = acc[i][j][ri] + bv;
                }
            } else if (MODE == 0) {
                u16* o = (u16*)out;
                const int hh = col >> 6, dd = col & 63;
#pragma unroll
                for (int ri = 0; ri < 4; ri++) {
                    int row = m0 + wr + i * 16 + lg * 4 + ri;
                    int bb = row >> 11, ss = row & 2047;
                    o[((size_t)(bb * H_NUM + hh) * S_LEN + ss) * D_DIM + dd] =
                        f2bf(acc[i][j][ri] + bv);
                }
            } else {  // MODE 1: V^T [B,H,D,S], pack 4 consecutive s as 8B store
                u16* o = (u16*)out;
                const int hh = col >> 6, dd = col & 63;
                int row0 = m0 + wr + i * 16 + lg * 4;
                int bb = row0 >> 11, ss = row0 & 2047;
                u16x4 pk;
#pragma unroll
                for (int ri = 0; ri < 4; ri++) pk[ri] = f2bf(acc[i][j][ri] + bv);
                *(u16x4*)&o[((size_t)(bb * H_NUM + hh) * D_DIM + dd) * S_LEN + ss] = pk;
            }
        }
    }
}

// ---------------- flash attention ----------------------------------------
// grid: (S/64, B*H). 4 waves/block, each wave owns 16 q-rows independently.
// Q,K: [B,H,S,D] bf16; Vt: [B,H,D,S] bf16; attn_out: [B*S, E] bf16.
__global__ __launch_bounds__(256) void attn_kernel(const u16* __restrict__ Qg,
                                                   const u16* __restrict__ Kg,
                                                   const u16* __restrict__ Vt,
                                                   u16* __restrict__ attn_out,
                                                   const int* __restrict__ actp) {
    const int bh = blockIdx.y, h = bh & (H_NUM - 1), b = bh >> 4;
    const int t = threadIdx.x, w = t >> 6, lane = t & 63;
    const int li = lane & 15, lg = lane >> 4;
    const int active = *actp;

    if (h >= active) {  // masked head: attn channels are exactly zero
        int row = blockIdx.x * 64 + (t >> 2);
        u16* dst = attn_out + (size_t)(b * S_LEN + row) * E_DIM + h * D_DIM + (t & 3) * 16;
        u16x8 z = {};
        *(u16x8*)dst = z;
        *(u16x8*)(dst + 8) = z;
        return;
    }

    const int q0 = blockIdx.x * 64 + w * 16;
    const size_t hoff = (size_t)(b * H_NUM + h) * S_LEN * D_DIM;
    const u16* Qh = Qg + hoff;
    const u16* Kh = Kg + hoff;
    const u16* Vh = Vt + hoff;  // [D][S]

    __shared__ __align__(16) u16 Pl[4][16][72];  // per-wave P tile, padded (2-way = free)

    bf16x8 qf[2];
#pragma unroll
    for (int kt = 0; kt < 2; kt++)
        qf[kt] = *(const bf16x8*)&Qh[(size_t)(q0 + li) * D_DIM + kt * 32 + lg * 8];

    f32x4 acc_o[4] = {};
    float m_run[4], l_run[4];
#pragma unroll
    for (int ri = 0; ri < 4; ri++) { m_run[ri] = -1e30f; l_run[ri] = 0.f; }

    for (int kv0 = 0; kv0 < S_LEN; kv0 += 64) {
        // ---- scores: S = Q K^T * 0.125 ; D-layout row=(lg*4+ri)=q, col=li=kv
        f32x4 sc[4] = {};
#pragma unroll
        for (int ct = 0; ct < 4; ct++) {
#pragma unroll
            for (int kt = 0; kt < 2; kt++) {
                bf16x8 kf = *(const bf16x8*)&Kh[(size_t)(kv0 + ct * 16 + li) * D_DIM + kt * 32 + lg * 8];
                sc[ct] = __builtin_amdgcn_mfma_f32_16x16x32_bf16(qf[kt], kf, sc[ct], 0, 0, 0);
            }
        }
#pragma unroll
        for (int ct = 0; ct < 4; ct++) sc[ct] *= 0.125f;

        // ---- online softmax stats (row reduce over 16 lanes of the group)
        float corr[4];
#pragma unroll
        for (int ri = 0; ri < 4; ri++) {
            float mx = fmaxf(fmaxf(sc[0][ri], sc[1][ri]), fmaxf(sc[2][ri], sc[3][ri]));
#pragma unroll
            for (int d = 1; d < 16; d <<= 1) mx = fmaxf(mx, __shfl_xor(mx, d, 64));
            float mnew = fmaxf(m_run[ri], mx);
            corr[ri] = __expf(m_run[ri] - mnew);
            m_run[ri] = mnew;
        }

        // WAR: previous iteration's P reads must drain before overwrite
        asm volatile("s_waitcnt lgkmcnt(0)" ::: "memory");

        float lsum[4];
#pragma unroll
        for (int ri = 0; ri < 4; ri++) lsum[ri] = 0.f;
#pragma unroll
        for (int ct = 0; ct < 4; ct++) {
#pragma unroll
            for (int ri = 0; ri < 4; ri++) {
                float p = __expf(sc[ct][ri] - m_run[ri]);
                lsum[ri] += p;
                Pl[w][lg * 4 + ri][ct * 16 + li] = f2bf(p);
            }
        }
#pragma unroll
        for (int ri = 0; ri < 4; ri++) {
            float s = lsum[ri];
#pragma unroll
            for (int d = 1; d < 16; d <<= 1) s += __shfl_xor(s, d, 64);
            l_run[ri] = l_run[ri] * corr[ri] + s;
        }
#pragma unroll
        for (int dt = 0; dt < 4; dt++)
#pragma unroll
            for (int ri = 0; ri < 4; ri++) acc_o[dt][ri] *= corr[ri];

        // RAW: P writes visible before fragment reads (cross-lane, same wave)
        asm volatile("s_waitcnt lgkmcnt(0)" ::: "memory");

        bf16x8 pf[2];
#pragma unroll
        for (int kt = 0; kt < 2; kt++)
            pf[kt] = *(const bf16x8*)&Pl[w][li][kt * 32 + lg * 8];
#pragma unroll
        for (int dt = 0; dt < 4; dt++) {
#pragma unroll
            for (int kt = 0; kt < 2; kt++) {
                bf16x8 vf = *(const bf16x8*)&Vh[(size_t)(dt * 16 + li) * S_LEN + kv0 + kt * 32 + lg * 8];
                acc_o[dt] = __builtin_amdgcn_mfma_f32_16x16x32_bf16(pf[kt], vf, acc_o[dt], 0, 0, 0);
            }
        }
    }

    // ---- epilogue: normalize and store bf16 to attn buffer [B*S, E]
#pragma unroll
    for (int ri = 0; ri < 4; ri++) {
        float inv = 1.0f / l_run[ri];
        int row = q0 + lg * 4 + ri;
        u16* dst = attn_out + (size_t)(b * S_LEN + row) * E_DIM + h * D_DIM;
#pragma unroll
        for (int dt = 0; dt < 4; dt++)
            dst[dt * 16 + li] = f2bf(acc_o[dt][ri] * inv);
    }
}

// ---------------- launcher ------------------------------------------------
extern "C" void kernel_launch(void* const* d_in, const int* in_sizes, int n_in,
                              void* d_out, int out_size, void* d_ws, size_t ws_size,
                              hipStream_t stream) {
    const float* hidden = (const float*)d_in[0];
    const float* Wq = (const float*)d_in[1];
    const float* bq = (const float*)d_in[2];
    const float* Wk = (const float*)d_in[3];
    const float* bk = (const float*)d_in[4];
    const float* Wv = (const float*)d_in[5];
    const float* bv = (const float*)d_in[6];
    const float* Wo = (const float*)d_in[7];
    const float* bo = (const float*)d_in[8];
    const int* act = (const int*)d_in[9];

    u16* ws = (u16*)d_ws;
    u16* Xb = ws;                    // [8192,1024] bf16
    u16* Wqb = Xb + 8388608;
    u16* Wkb = Wqb + 1048576;
    u16* Wvb = Wkb + 1048576;
    u16* Wob = Wvb + 1048576;
    u16* Qb = Wob + 1048576;         // [B,H,S,D]
    u16* Kb = Qb + 8388608;          // [B,H,S,D]
    u16* Vtb = Kb + 8388608;         // [B,H,D,S]
    u16* Att = Vtb + 8388608;        // [8192,1024]

    cvt_kernel<<<2048, 256, 0, stream>>>(hidden, Xb, 8388608 / 4);
    cvt_kernel<<<512, 256, 0, stream>>>(Wq, Wqb, 1048576 / 4);
    cvt_kernel<<<512, 256, 0, stream>>>(Wk, Wkb, 1048576 / 4);
    cvt_kernel<<<512, 256, 0, stream>>>(Wv, Wvb, 1048576 / 4);
    cvt_kernel<<<512, 256, 0, stream>>>(Wo, Wob, 1048576 / 4);

    dim3 g(E_DIM / 128, M_DIM / 128);  // (8, 64)
    gemm_nt<0><<<g, 256, 0, stream>>>(Xb, Wqb, bq, Qb);
    gemm_nt<0><<<g, 256, 0, stream>>>(Xb, Wkb, bk, Kb);
    gemm_nt<1><<<g, 256, 0, stream>>>(Xb, Wvb, bv, Vtb);

    attn_kernel<<<dim3(S_LEN / 64, B_NUM * H_NUM), 256, 0, stream>>>(Qb, Kb, Vtb, Att, act);

    gemm_nt<2><<<g, 256, 0, stream>>>(Att, Wob, bo, d_out);
}

// Round 6
// 315.905 us; speedup vs baseline: 1.5163x; 1.5163x over previous
//
#include <hip/hip_runtime.h>
#include <hip/hip_bf16.h>
#include <stdint.h>

#define E_DIM 1024
#define H_NUM 16
#define D_DIM 64
#define B_NUM 4
#define S_LEN 2048
#define M_DIM (B_NUM * S_LEN)  // 8192

typedef short bf16x8 __attribute__((ext_vector_type(8)));
typedef float f32x4 __attribute__((ext_vector_type(4)));
typedef float f32x16 __attribute__((ext_vector_type(16)));
typedef unsigned short u16;
typedef unsigned int u32;
typedef u16 u16x4 __attribute__((ext_vector_type(4)));
typedef u16 u16x8 __attribute__((ext_vector_type(8)));
typedef float fl4 __attribute__((ext_vector_type(4)));

typedef const __attribute__((address_space(1))) void* gas_ptr;
typedef __attribute__((address_space(3))) void* las_ptr;

__device__ __forceinline__ u16 f2bf(float f) {
    uint32_t u = __builtin_bit_cast(uint32_t, f);
    u += 0x7fffu + ((u >> 16) & 1u);   // RNE (inputs finite)
    return (u16)(u >> 16);
}

__device__ __forceinline__ void gload16(const u16* g, u16* l) {
    __builtin_amdgcn_global_load_lds((gas_ptr)g, (las_ptr)l, 16, 0, 0);
}

// ---------------- fp32 -> bf16 conversion (vectorized x4) ----------------
__global__ __launch_bounds__(256) void cvt_kernel(const float* __restrict__ in,
                                                  u16* __restrict__ out, int n4) {
    int idx = blockIdx.x * 256 + threadIdx.x;
    int stride = gridDim.x * 256;
    for (int i = idx; i < n4; i += stride) {
        fl4 v = ((const fl4*)in)[i];
        u16x4 o;
#pragma unroll
        for (int j = 0; j < 4; j++) o[j] = f2bf(v[j]);
        ((u16x4*)out)[i] = o;
    }
}

// ---------------- NT GEMM: C[m,n] = sum_k A[m,k]*B[n,k] + bias[n] --------
// MODE 0: bf16 out at [B,H,S,D] (Q,K) | MODE 1: bf16 out [B,H,D,S] (V^T)
// MODE 2: fp32 out at [M,E] (final)
template <int MODE>
__global__ __launch_bounds__(256) void gemm_nt(const u16* __restrict__ A,
                                               const u16* __restrict__ Bw,
                                               const float* __restrict__ bias,
                                               void* __restrict__ out) {
    __shared__ u16 Ash[128 * 32];
    __shared__ u16 Bsh[128 * 32];
    const int t = threadIdx.x, w = t >> 6, lane = t & 63;
    const int li = lane & 15, lg = lane >> 4;
    const int m0 = blockIdx.y * 128, n0 = blockIdx.x * 128;
    const int K = 1024;
    const int srow = lane >> 2, scol = (lane & 3) * 8;
    const int wr = (w >> 1) * 64, wc = (w & 1) * 64;
    f32x4 acc[4][4] = {};

    for (int k0 = 0; k0 < K; k0 += 32) {
#pragma unroll
        for (int r = 0; r < 2; r++) {
            int rowbase = r * 64 + w * 16;
            gload16(A + (size_t)(m0 + rowbase + srow) * K + k0 + scol, &Ash[rowbase * 32]);
            gload16(Bw + (size_t)(n0 + rowbase + srow) * K + k0 + scol, &Bsh[rowbase * 32]);
        }
        __syncthreads();
        bf16x8 af[4], bfr[4];
#pragma unroll
        for (int i = 0; i < 4; i++)
            af[i] = *(const bf16x8*)&Ash[(wr + i * 16 + li) * 32 + lg * 8];
#pragma unroll
        for (int j = 0; j < 4; j++)
            bfr[j] = *(const bf16x8*)&Bsh[(wc + j * 16 + li) * 32 + lg * 8];
#pragma unroll
        for (int i = 0; i < 4; i++)
#pragma unroll
            for (int j = 0; j < 4; j++)
                acc[i][j] = __builtin_amdgcn_mfma_f32_16x16x32_bf16(af[i], bfr[j], acc[i][j], 0, 0, 0);
        __syncthreads();
    }

#pragma unroll
    for (int i = 0; i < 4; i++) {
#pragma unroll
        for (int j = 0; j < 4; j++) {
            const int col = n0 + wc + j * 16 + li;
            const float bv = bias[col];
            if (MODE == 2) {
                float* o = (float*)out;
#pragma unroll
                for (int ri = 0; ri < 4; ri++) {
                    int row = m0 + wr + i * 16 + lg * 4 + ri;
                    o[(size_t)row * E_DIM + col] = acc[i][j][ri] + bv;
                }
            } else if (MODE == 0) {
                u16* o = (u16*)out;
                const int hh = col >> 6, dd = col & 63;
#pragma unroll
                for (int ri = 0; ri < 4; ri++) {
                    int row = m0 + wr + i * 16 + lg * 4 + ri;
                    int bb = row >> 11, ss = row & 2047;
                    o[((size_t)(bb * H_NUM + hh) * S_LEN + ss) * D_DIM + dd] =
                        f2bf(acc[i][j][ri] + bv);
                }
            } else {  // MODE 1: V^T [B,H,D,S]
                u16* o = (u16*)out;
                const int hh = col >> 6, dd = col & 63;
                int row0 = m0 + wr + i * 16 + lg * 4;
                int bb = row0 >> 11, ss = row0 & 2047;
                u16x4 pk;
#pragma unroll
                for (int ri = 0; ri < 4; ri++) pk[ri] = f2bf(acc[i][j][ri] + bv);
                *(u16x4*)&o[((size_t)(bb * H_NUM + hh) * D_DIM + dd) * S_LEN + ss] = pk;
            }
        }
    }
}

// ---------------- flash attention, swapped-QK^T, LDS-staged P ------------
// BISECT build: identical to round-5 EXCEPT the PV B-fragment is staged
// through per-warp XOR-swizzled LDS (P^T[q][kv] rows of 128B) instead of
// permlane32_swap assembly; cross-half max/sum via __shfl_xor(.,32).
// Zero permlane / cvtpk in this kernel.
__global__ __launch_bounds__(256) void attn_kernel(const u16* __restrict__ Qg,
                                                   const u16* __restrict__ Kg,
                                                   const u16* __restrict__ Vt,
                                                   u16* __restrict__ attn_out,
                                                   const int* __restrict__ actp) {
    const int bh = blockIdx.y, h = bh & (H_NUM - 1), b = bh >> 4;
    const int t = threadIdx.x, w = t >> 6, lane = t & 63;
    const int ql = lane & 31, hi = lane >> 5;
    const int active = *actp;

    if (h >= active) {  // masked head: attn channels exactly zero
        int row = blockIdx.x * 128 + (t >> 1);
        u16* dst = attn_out + (size_t)(b * S_LEN + row) * E_DIM + h * D_DIM + (t & 1) * 32;
        u16x8 z = {};
        *(u16x8*)(dst + 0) = z;
        *(u16x8*)(dst + 8) = z;
        *(u16x8*)(dst + 16) = z;
        *(u16x8*)(dst + 24) = z;
        return;
    }

    const int q0 = blockIdx.x * 128 + w * 32;
    const size_t hoff = (size_t)(b * H_NUM + h) * S_LEN * D_DIM;
    const u16* Qh = Qg + hoff;
    const u16* Kh = Kg + hoff;
    const u16* Vh = Vt + hoff;  // [D][S]

    // per-warp P^T tile: 32 q-rows x 64 kv, row = 128 B, XOR-swizzled bit4-6
    __shared__ __align__(16) u16 Pl[4][32 * 64];
    char* Pw_base = (char*)&Pl[w][0] + ql * 128;
    const int sw = (ql & 7) << 4;

    // Q fragments (B-operand): lane holds Q[q0+ql][dch*16 + hi*8 + j]
    bf16x8 qf[4];
#pragma unroll
    for (int dch = 0; dch < 4; dch++)
        qf[dch] = *(const bf16x8*)&Qh[(size_t)(q0 + ql) * D_DIM + dch * 16 + hi * 8];

    f32x16 o0 = {}, o1 = {};
    float m_run = -1e30f, l_run = 0.f;
    const float Cs = 0.125f * 1.44269504f;  // scale * log2(e)

    for (int kv0 = 0; kv0 < S_LEN; kv0 += 64) {
        // ---- S^T tiles: rows kv (from K as A), cols q (from Q as B)
        const u16* Kp = Kh + (size_t)(kv0 + ql) * D_DIM;
        f32x16 s0 = {}, s1 = {};
#pragma unroll
        for (int dch = 0; dch < 4; dch++) {
            bf16x8 k0 = *(const bf16x8*)(Kp + dch * 16 + hi * 8);
            bf16x8 k1 = *(const bf16x8*)(Kp + 32 * D_DIM + dch * 16 + hi * 8);
            s0 = __builtin_amdgcn_mfma_f32_32x32x16_bf16(k0, qf[dch], s0, 0, 0, 0);
            s1 = __builtin_amdgcn_mfma_f32_32x32x16_bf16(k1, qf[dch], s1, 0, 0, 0);
        }

        // ---- lane-local max over 32 kv + cross-half combine (shfl_xor 32)
        float mx = fmaxf(s0[0], s1[0]);
#pragma unroll
        for (int r = 1; r < 16; r++) mx = fmaxf(mx, fmaxf(s0[r], s1[r]));
        mx = fmaxf(mx, __shfl_xor(mx, 32, 64));

        // ---- ALWAYS rescale to the true running max (round-1 semantics)
        {
            float mnew = fmaxf(m_run, mx);
            float corr = __builtin_amdgcn_exp2f((m_run - mnew) * Cs);
            m_run = mnew;
            l_run *= corr;
#pragma unroll
            for (int r = 0; r < 16; r++) { o0[r] *= corr; o1[r] *= corr; }
        }
        const float mt = m_run * Cs;

        // ---- P = exp2(Cs*s - mt) <= 1; pack pairs via f2bf (RNE)
        u32 pk0[8], pk1[8];
        float ls = 0.f;
#pragma unroll
        for (int i = 0; i < 8; i++) {
            float a0 = __builtin_amdgcn_exp2f(__builtin_fmaf(s0[2 * i], Cs, -mt));
            float b0 = __builtin_amdgcn_exp2f(__builtin_fmaf(s0[2 * i + 1], Cs, -mt));
            float a1 = __builtin_amdgcn_exp2f(__builtin_fmaf(s1[2 * i], Cs, -mt));
            float b1 = __builtin_amdgcn_exp2f(__builtin_fmaf(s1[2 * i + 1], Cs, -mt));
            ls += (a0 + b0) + (a1 + b1);
            pk0[i] = (u32)f2bf(a0) | ((u32)f2bf(b0) << 16);
            pk1[i] = (u32)f2bf(a1) | ((u32)f2bf(b1) << 16);
        }
        ls += __shfl_xor(ls, 32, 64);
        l_run += ls;

        // ---- WAR: previous tile's P reads must drain before overwrite
        asm volatile("s_waitcnt lgkmcnt(0)" ::: "memory");
        __builtin_amdgcn_sched_barrier(0);

        // ---- store P^T pairs to own q-row: kv = 8*(i>>1) + 4*hi + 2*(i&1)
#pragma unroll
        for (int i = 0; i < 8; i++) {
            const int kvb = (8 * (i >> 1) + 4 * hi + 2 * (i & 1)) * 2;  // byte off
            *(u32*)(Pw_base + (kvb ^ sw)) = pk0[i];
            *(u32*)(Pw_base + ((kvb + 64) ^ sw)) = pk1[i];
        }

        // ---- RAW: P writes (incl. other hi-half lane's) visible
        asm volatile("s_waitcnt lgkmcnt(0)" ::: "memory");
        __builtin_amdgcn_sched_barrier(0);

        // ---- PV: O^T += V^T x P^T ; B-frag = 16B LDS read per chunk
        const u16* Vp = Vh + kv0;
#pragma unroll
        for (int c = 0; c < 4; c++) {
            bf16x8 pb = *(const bf16x8*)(Pw_base + ((c * 32 + hi * 16) ^ sw));
            bf16x8 v0 = *(const bf16x8*)(Vp + (size_t)ql * S_LEN + c * 16 + hi * 8);
            bf16x8 v1 = *(const bf16x8*)(Vp + (size_t)(32 + ql) * S_LEN + c * 16 + hi * 8);
            o0 = __builtin_amdgcn_mfma_f32_32x32x16_bf16(v0, pb, o0, 0, 0, 0);
            o1 = __builtin_amdgcn_mfma_f32_32x32x16_bf16(v1, pb, o1, 0, 0, 0);
        }
    }

    // ---- epilogue: normalize, bf16, store [B*S, E]
    const float inv = 1.0f / l_run;
    u16* dst = attn_out + (size_t)(b * S_LEN + q0 + ql) * E_DIM + h * D_DIM;
#pragma unroll
    for (int g = 0; g < 4; g++) {
        u16x4 w0, w1;
#pragma unroll
        for (int e = 0; e < 4; e++) {
            w0[e] = f2bf(o0[4 * g + e] * inv);
            w1[e] = f2bf(o1[4 * g + e] * inv);
        }
        *(u16x4*)(dst + 8 * g + 4 * hi) = w0;
        *(u16x4*)(dst + 32 + 8 * g + 4 * hi) = w1;
    }
}

// ---------------- launcher ------------------------------------------------
extern "C" void kernel_launch(void* const* d_in, const int* in_sizes, int n_in,
                              void* d_out, int out_size, void* d_ws, size_t ws_size,
                              hipStream_t stream) {
    const float* hidden = (const float*)d_in[0];
    const float* Wq = (const float*)d_in[1];
    const float* bq = (const float*)d_in[2];
    const float* Wk = (const float*)d_in[3];
    const float* bk = (const float*)d_in[4];
    const float* Wv = (const float*)d_in[5];
    const float* bv = (const float*)d_in[6];
    const float* Wo = (const float*)d_in[7];
    const float* bo = (const float*)d_in[8];
    const int* act = (const int*)d_in[9];

    u16* ws = (u16*)d_ws;
    u16* Xb = ws;                    // [8192,1024] bf16
    u16* Wqb = Xb + 8388608;
    u16* Wkb = Wqb + 1048576;
    u16* Wvb = Wkb + 1048576;
    u16* Wob = Wvb + 1048576;
    u16* Qb = Wob + 1048576;         // [B,H,S,D]
    u16* Kb = Qb + 8388608;          // [B,H,S,D]
    u16* Vtb = Kb + 8388608;         // [B,H,D,S]
    u16* Att = Vtb + 8388608;        // [8192,1024]

    cvt_kernel<<<2048, 256, 0, stream>>>(hidden, Xb, 8388608 / 4);
    cvt_kernel<<<512, 256, 0, stream>>>(Wq, Wqb, 1048576 / 4);
    cvt_kernel<<<512, 256, 0, stream>>>(Wk, Wkb, 1048576 / 4);
    cvt_kernel<<<512, 256, 0, stream>>>(Wv, Wvb, 1048576 / 4);
    cvt_kernel<<<512, 256, 0, stream>>>(Wo, Wob, 1048576 / 4);

    dim3 g(E_DIM / 128, M_DIM / 128);  // (8, 64)
    gemm_nt<0><<<g, 256, 0, stream>>>(Xb, Wqb, bq, Qb);
    gemm_nt<0><<<g, 256, 0, stream>>>(Xb, Wkb, bk, Kb);
    gemm_nt<1><<<g, 256, 0, stream>>>(Xb, Wvb, bv, Vtb);

    attn_kernel<<<dim3(S_LEN / 128, B_NUM * H_NUM), 256, 0, stream>>>(Qb, Kb, Vtb, Att, act);

    gemm_nt<2><<<g, 256, 0, stream>>>(Att, Wob, bo, d_out);
}

// Round 7
// 315.040 us; speedup vs baseline: 1.5205x; 1.0027x over previous
//
#include <hip/hip_runtime.h>
#include <hip/hip_bf16.h>
#include <stdint.h>

#define E_DIM 1024
#define H_NUM 16
#define D_DIM 64
#define B_NUM 4
#define S_LEN 2048
#define M_DIM (B_NUM * S_LEN)  // 8192

typedef short bf16x8 __attribute__((ext_vector_type(8)));
typedef float f32x4 __attribute__((ext_vector_type(4)));
typedef float f32x16 __attribute__((ext_vector_type(16)));
typedef unsigned short u16;
typedef unsigned int u32;
typedef u16 u16x4 __attribute__((ext_vector_type(4)));
typedef u16 u16x8 __attribute__((ext_vector_type(8)));
typedef float fl4 __attribute__((ext_vector_type(4)));

typedef const __attribute__((address_space(1))) void* gas_ptr;
typedef __attribute__((address_space(3))) void* las_ptr;

__device__ __forceinline__ u16 f2bf(float f) {
    uint32_t u = __builtin_bit_cast(uint32_t, f);
    u += 0x7fffu + ((u >> 16) & 1u);   // RNE (inputs finite)
    return (u16)(u >> 16);
}

__device__ __forceinline__ void gload16(const u16* g, u16* l) {
    __builtin_amdgcn_global_load_lds((gas_ptr)g, (las_ptr)l, 16, 0, 0);
}

// ---------------- fp32 -> bf16 conversion (vectorized x4) ----------------
__global__ __launch_bounds__(256) void cvt_kernel(const float* __restrict__ in,
                                                  u16* __restrict__ out, int n4) {
    int idx = blockIdx.x * 256 + threadIdx.x;
    int stride = gridDim.x * 256;
    for (int i = idx; i < n4; i += stride) {
        fl4 v = ((const fl4*)in)[i];
        u16x4 o;
#pragma unroll
        for (int j = 0; j < 4; j++) o[j] = f2bf(v[j]);
        ((u16x4*)out)[i] = o;
    }
}

// ---------------- NT GEMM: C[m,n] = sum_k A[m,k]*B[n,k] + bias[n] --------
// MODE 0: bf16 out at [B,H,S,D] (Q,K) | MODE 1: bf16 out [B,H,D,S] (V^T)
// MODE 2: fp32 out at [M,E] (final)
template <int MODE>
__global__ __launch_bounds__(256) void gemm_nt(const u16* __restrict__ A,
                                               const u16* __restrict__ Bw,
                                               const float* __restrict__ bias,
                                               void* __restrict__ out) {
    __shared__ u16 Ash[128 * 32];
    __shared__ u16 Bsh[128 * 32];
    const int t = threadIdx.x, w = t >> 6, lane = t & 63;
    const int li = lane & 15, lg = lane >> 4;
    const int m0 = blockIdx.y * 128, n0 = blockIdx.x * 128;
    const int K = 1024;
    const int srow = lane >> 2, scol = (lane & 3) * 8;
    const int wr = (w >> 1) * 64, wc = (w & 1) * 64;
    f32x4 acc[4][4] = {};

    for (int k0 = 0; k0 < K; k0 += 32) {
#pragma unroll
        for (int r = 0; r < 2; r++) {
            int rowbase = r * 64 + w * 16;
            gload16(A + (size_t)(m0 + rowbase + srow) * K + k0 + scol, &Ash[rowbase * 32]);
            gload16(Bw + (size_t)(n0 + rowbase + srow) * K + k0 + scol, &Bsh[rowbase * 32]);
        }
        __syncthreads();
        bf16x8 af[4], bfr[4];
#pragma unroll
        for (int i = 0; i < 4; i++)
            af[i] = *(const bf16x8*)&Ash[(wr + i * 16 + li) * 32 + lg * 8];
#pragma unroll
        for (int j = 0; j < 4; j++)
            bfr[j] = *(const bf16x8*)&Bsh[(wc + j * 16 + li) * 32 + lg * 8];
#pragma unroll
        for (int i = 0; i < 4; i++)
#pragma unroll
            for (int j = 0; j < 4; j++)
                acc[i][j] = __builtin_amdgcn_mfma_f32_16x16x32_bf16(af[i], bfr[j], acc[i][j], 0, 0, 0);
        __syncthreads();
    }

#pragma unroll
    for (int i = 0; i < 4; i++) {
#pragma unroll
        for (int j = 0; j < 4; j++) {
            const int col = n0 + wc + j * 16 + li;
            const float bv = bias[col];
            if (MODE == 2) {
                float* o = (float*)out;
#pragma unroll
                for (int ri = 0; ri < 4; ri++) {
                    int row = m0 + wr + i * 16 + lg * 4 + ri;
                    o[(size_t)row * E_DIM + col] = acc[i][j][ri] + bv;
                }
            } else if (MODE == 0) {
                u16* o = (u16*)out;
                const int hh = col >> 6, dd = col & 63;
#pragma unroll
                for (int ri = 0; ri < 4; ri++) {
                    int row = m0 + wr + i * 16 + lg * 4 + ri;
                    int bb = row >> 11, ss = row & 2047;
                    o[((size_t)(bb * H_NUM + hh) * S_LEN + ss) * D_DIM + dd] =
                        f2bf(acc[i][j][ri] + bv);
                }
            } else {  // MODE 1: V^T [B,H,D,S]
                u16* o = (u16*)out;
                const int hh = col >> 6, dd = col & 63;
                int row0 = m0 + wr + i * 16 + lg * 4;
                int bb = row0 >> 11, ss = row0 & 2047;
                u16x4 pk;
#pragma unroll
                for (int ri = 0; ri < 4; ri++) pk[ri] = f2bf(acc[i][j][ri] + bv);
                *(u16x4*)&o[((size_t)(bb * H_NUM + hh) * D_DIM + dd) * S_LEN + ss] = pk;
            }
        }
    }
}

// ---------------- flash attention, swapped-QK^T, pipelined ---------------
// Same verified dataflow as round-6 (32x32 MFMA, XOR-swizzled LDS P,
// always-rescale softmax). New: software pipeline — K frags double-buffered
// in registers (prefetch t+1 under softmax/PV of t), V frags prefetched at
// tile top, P double-buffered in LDS (single lgkmcnt drain per tile).
__global__ __launch_bounds__(256, 2) void attn_kernel(const u16* __restrict__ Qg,
                                                      const u16* __restrict__ Kg,
                                                      const u16* __restrict__ Vt,
                                                      u16* __restrict__ attn_out,
                                                      const int* __restrict__ actp) {
    const int bh = blockIdx.y, h = bh & (H_NUM - 1), b = bh >> 4;
    const int t = threadIdx.x, w = t >> 6, lane = t & 63;
    const int ql = lane & 31, hi = lane >> 5;
    const int active = *actp;

    if (h >= active) {  // masked head: attn channels exactly zero
        int row = blockIdx.x * 128 + (t >> 1);
        u16* dst = attn_out + (size_t)(b * S_LEN + row) * E_DIM + h * D_DIM + (t & 1) * 32;
        u16x8 z = {};
        *(u16x8*)(dst + 0) = z;
        *(u16x8*)(dst + 8) = z;
        *(u16x8*)(dst + 16) = z;
        *(u16x8*)(dst + 24) = z;
        return;
    }

    const int q0 = blockIdx.x * 128 + w * 32;
    const size_t hoff = (size_t)(b * H_NUM + h) * S_LEN * D_DIM;
    const u16* Qh = Qg + hoff;
    const u16* Kh = Kg + hoff;
    const u16* Vh = Vt + hoff;  // [D][S]

    // per-warp P^T tile, DOUBLE buffered: 32 q-rows x 64 kv, 128B rows,
    // XOR-swizzled (bits 4-6 ^ (q&7)<<4)
    __shared__ __align__(16) u16 Pl[4][2][32 * 64];
    char* Pb0 = (char*)&Pl[w][0][0] + ql * 128;
    char* Pb1 = (char*)&Pl[w][1][0] + ql * 128;
    const int sw = (ql & 7) << 4;

    // Q fragments (B-operand): lane holds Q[q0+ql][dch*16 + hi*8 + j]
    bf16x8 qf[4];
#pragma unroll
    for (int dch = 0; dch < 4; dch++)
        qf[dch] = *(const bf16x8*)&Qh[(size_t)(q0 + ql) * D_DIM + dch * 16 + hi * 8];

    f32x16 o0 = {}, o1 = {};
    float m_run = -1e30f, l_run = 0.f;
    const float Cs = 0.125f * 1.44269504f;  // scale * log2(e)

    bf16x8 kfA[8], kfB[8], vf[8];

    // prologue: K frags for tile 0
    {
        const u16* Kp = Kh + (size_t)ql * D_DIM;
#pragma unroll
        for (int d = 0; d < 4; d++) {
            kfA[d] = *(const bf16x8*)(Kp + d * 16 + hi * 8);
            kfA[4 + d] = *(const bf16x8*)(Kp + 32 * D_DIM + d * 16 + hi * 8);
        }
    }

    auto tile_step = [&](int kv0, bf16x8* kfC, bf16x8* kfN, char* Pb) {
        // ---- QK^T from prefetched K frags
        f32x16 s0 = {}, s1 = {};
#pragma unroll
        for (int d = 0; d < 4; d++) {
            s0 = __builtin_amdgcn_mfma_f32_32x32x16_bf16(kfC[d], qf[d], s0, 0, 0, 0);
            s1 = __builtin_amdgcn_mfma_f32_32x32x16_bf16(kfC[4 + d], qf[d], s1, 0, 0, 0);
        }

        // ---- prefetch K(t+1) and V(t) NOW; consumed after softmax
        {
            const int nkv = (kv0 + 64) & (S_LEN - 1);
            const u16* Kp = Kh + (size_t)(nkv + ql) * D_DIM;
#pragma unroll
            for (int d = 0; d < 4; d++) {
                kfN[d] = *(const bf16x8*)(Kp + d * 16 + hi * 8);
                kfN[4 + d] = *(const bf16x8*)(Kp + 32 * D_DIM + d * 16 + hi * 8);
            }
            const u16* Vp = Vh + kv0;
#pragma unroll
            for (int c = 0; c < 4; c++) {
                vf[c] = *(const bf16x8*)(Vp + (size_t)ql * S_LEN + c * 16 + hi * 8);
                vf[4 + c] = *(const bf16x8*)(Vp + (size_t)(32 + ql) * S_LEN + c * 16 + hi * 8);
            }
        }

        // ---- lane-local max + cross-half combine
        float mx = fmaxf(s0[0], s1[0]);
#pragma unroll
        for (int r = 1; r < 16; r++) mx = fmaxf(mx, fmaxf(s0[r], s1[r]));
        mx = fmaxf(mx, __shfl_xor(mx, 32, 64));

        // ---- always rescale to true running max
        {
            float mnew = fmaxf(m_run, mx);
            float corr = __builtin_amdgcn_exp2f((m_run - mnew) * Cs);
            m_run = mnew;
            l_run *= corr;
#pragma unroll
            for (int r = 0; r < 16; r++) { o0[r] *= corr; o1[r] *= corr; }
        }
        const float mt = m_run * Cs;

        // ---- P = exp2(Cs*s - mt) <= 1; pack pairs via f2bf (RNE)
        u32 pk0[8], pk1[8];
        float ls = 0.f;
#pragma unroll
        for (int i = 0; i < 8; i++) {
            float a0 = __builtin_amdgcn_exp2f(__builtin_fmaf(s0[2 * i], Cs, -mt));
            float b0 = __builtin_amdgcn_exp2f(__builtin_fmaf(s0[2 * i + 1], Cs, -mt));
            float a1 = __builtin_amdgcn_exp2f(__builtin_fmaf(s1[2 * i], Cs, -mt));
            float b1 = __builtin_amdgcn_exp2f(__builtin_fmaf(s1[2 * i + 1], Cs, -mt));
            ls += (a0 + b0) + (a1 + b1);
            pk0[i] = (u32)f2bf(a0) | ((u32)f2bf(b0) << 16);
            pk1[i] = (u32)f2bf(a1) | ((u32)f2bf(b1) << 16);
        }
        ls += __shfl_xor(ls, 32, 64);
        l_run += ls;

        // ---- store P^T to this tile's LDS buffer (alternates => no WAR wait)
#pragma unroll
        for (int i = 0; i < 8; i++) {
            const int kvb = (8 * (i >> 1) + 4 * hi + 2 * (i & 1)) * 2;  // byte off
            *(u32*)(Pb + (kvb ^ sw)) = pk0[i];
            *(u32*)(Pb + ((kvb + 64) ^ sw)) = pk1[i];
        }

        // ---- RAW: all prior DS ops (in-order) drained; then PV reads
        asm volatile("s_waitcnt lgkmcnt(0)" ::: "memory");
        __builtin_amdgcn_sched_barrier(0);

        // ---- PV: O^T += V^T x P^T ; B-frag = 16B LDS read per chunk
#pragma unroll
        for (int c = 0; c < 4; c++) {
            bf16x8 pb = *(const bf16x8*)(Pb + ((c * 32 + hi * 16) ^ sw));
            o0 = __builtin_amdgcn_mfma_f32_32x32x16_bf16(vf[c], pb, o0, 0, 0, 0);
            o1 = __builtin_amdgcn_mfma_f32_32x32x16_bf16(vf[4 + c], pb, o1, 0, 0, 0);
        }
    };

    for (int kv0 = 0; kv0 < S_LEN; kv0 += 128) {
        tile_step(kv0, kfA, kfB, Pb0);
        tile_step(kv0 + 64, kfB, kfA, Pb1);
    }

    // ---- epilogue: normalize, bf16, store [B*S, E]
    const float inv = 1.0f / l_run;
    u16* dst = attn_out + (size_t)(b * S_LEN + q0 + ql) * E_DIM + h * D_DIM;
#pragma unroll
    for (int g = 0; g < 4; g++) {
        u16x4 w0, w1;
#pragma unroll
        for (int e = 0; e < 4; e++) {
            w0[e] = f2bf(o0[4 * g + e] * inv);
            w1[e] = f2bf(o1[4 * g + e] * inv);
        }
        *(u16x4*)(dst + 8 * g + 4 * hi) = w0;
        *(u16x4*)(dst + 32 + 8 * g + 4 * hi) = w1;
    }
}

// ---------------- launcher ------------------------------------------------
extern "C" void kernel_launch(void* const* d_in, const int* in_sizes, int n_in,
                              void* d_out, int out_size, void* d_ws, size_t ws_size,
                              hipStream_t stream) {
    const float* hidden = (const float*)d_in[0];
    const float* Wq = (const float*)d_in[1];
    const float* bq = (const float*)d_in[2];
    const float* Wk = (const float*)d_in[3];
    const float* bk = (const float*)d_in[4];
    const float* Wv = (const float*)d_in[5];
    const float* bv = (const float*)d_in[6];
    const float* Wo = (const float*)d_in[7];
    const float* bo = (const float*)d_in[8];
    const int* act = (const int*)d_in[9];

    u16* ws = (u16*)d_ws;
    u16* Xb = ws;                    // [8192,1024] bf16
    u16* Wqb = Xb + 8388608;
    u16* Wkb = Wqb + 1048576;
    u16* Wvb = Wkb + 1048576;
    u16* Wob = Wvb + 1048576;
    u16* Qb = Wob + 1048576;         // [B,H,S,D]
    u16* Kb = Qb + 8388608;          // [B,H,S,D]
    u16* Vtb = Kb + 8388608;         // [B,H,D,S]
    u16* Att = Vtb + 8388608;        // [8192,1024]

    cvt_kernel<<<2048, 256, 0, stream>>>(hidden, Xb, 8388608 / 4);
    cvt_kernel<<<512, 256, 0, stream>>>(Wq, Wqb, 1048576 / 4);
    cvt_kernel<<<512, 256, 0, stream>>>(Wk, Wkb, 1048576 / 4);
    cvt_kernel<<<512, 256, 0, stream>>>(Wv, Wvb, 1048576 / 4);
    cvt_kernel<<<512, 256, 0, stream>>>(Wo, Wob, 1048576 / 4);

    dim3 g(E_DIM / 128, M_DIM / 128);  // (8, 64)
    gemm_nt<0><<<g, 256, 0, stream>>>(Xb, Wqb, bq, Qb);
    gemm_nt<0><<<g, 256, 0, stream>>>(Xb, Wkb, bk, Kb);
    gemm_nt<1><<<g, 256, 0, stream>>>(Xb, Wvb, bv, Vtb);

    attn_kernel<<<dim3(S_LEN / 128, B_NUM * H_NUM), 256, 0, stream>>>(Qb, Kb, Vtb, Att, act);

    gemm_nt<2><<<g, 256, 0, stream>>>(Att, Wob, bo, d_out);
}